// Round 5
// baseline (1211.753 us; speedup 1.0000x reference)
//
#include <hip/hip_runtime.h>

// Problem constants
#define HH   1024
#define WW   2048
#define HWP  (HH * WW)          // 2,097,152 pixels
#define CC   34
#define NI   128
#define THING_LO 24
#define THING_HI 33
#define NTC  10                 // thing classes 24..33

#define NW   (HWP / 4)          // 524,288 packed words (4 inst-bytes each)

// k1a: inst-byte compute, 256 blocks x 256 thr x 8 words
#define K1A_BLOCKS 256
#define K1A_WPT    8

// Fused post-k2 kernel: seg-role blocks first (read/latency-heavy), then
// mask-role streamer blocks.
#define NSEGCH     64                    // chunks per class plane
#define SEG_BLOCKS (NTC * NSEGCH)        // 640
#define CW3        (NW / NSEGCH)         // 8192 words per seg block

#define NCHUNK     16
#define CWORDS     (NW / NCHUNK)         // 32,768 words per mask chunk
#define CPIX       (HWP / NCHUNK)        // 131,072 pixels (512 KB contiguous)
#define MASK_BLOCKS (NI * NCHUNK)        // 2048
#define FUSED_BLOCKS (SEG_BLOCKS + MASK_BLOCKS)  // 2688

typedef float nfloat4 __attribute__((ext_vector_type(4)));

// Output layout (all float32, concatenated in return order)
#define OFF_CLASS  ((size_t)NI * HWP)
#define OFF_PROBS  (OFF_CLASS + NI)
#define OFF_SEGP   (OFF_PROBS + NI)
#define OFF_TOTAL  (OFF_SEGP + NI)
#define OFF_VALID  (OFF_TOTAL + NI)

// Workspace layout (bytes)
#define WS_COUNTS  0                         // int[NI*NTC] = 5120 B
#define WS_CLS     (NI * NTC * 4)            // int[NI]
#define WS_INV     (WS_CLS + NI * 4)         // float[NI]
#define WS_INST    8192                      // u32[NW] = 2 MB packed inst bytes

__device__ __forceinline__ int thing_inst(int s, int im) {
    return (s >= THING_LO && s <= THING_HI) ? im : 0;
}

// K1a: per-pixel instance id (u8, 0..128), packed 4/word into the 2 MB
// workspace; LDS-histogram (inst,class) counts, flushed once per block.
__global__ __launch_bounds__(256) void k1a_inst(
    const int* __restrict__ seg, const int* __restrict__ imap,
    uint32_t* __restrict__ instw, int* __restrict__ counts)
{
    __shared__ int hist[NI * NTC];   // 5 KB
    const int tid = threadIdx.x;
    for (int i = tid; i < NI * NTC; i += 256) hist[i] = 0;
    __syncthreads();

    const int base = blockIdx.x * (K1A_WPT * 256);
    #pragma unroll
    for (int j = 0; j < K1A_WPT; ++j) {
        const int q = base + j * 256 + tid;
        const int p = q * 4;
        const int4 sg = *reinterpret_cast<const int4*>(seg + p);
        const int4 im = *reinterpret_cast<const int4*>(imap + p);

        const int i0 = thing_inst(sg.x, im.x);
        const int i1 = thing_inst(sg.y, im.y);
        const int i2 = thing_inst(sg.z, im.z);
        const int i3 = thing_inst(sg.w, im.w);

        if (i0 > 0) atomicAdd(&hist[(i0 - 1) * NTC + (sg.x - THING_LO)], 1);
        if (i1 > 0) atomicAdd(&hist[(i1 - 1) * NTC + (sg.y - THING_LO)], 1);
        if (i2 > 0) atomicAdd(&hist[(i2 - 1) * NTC + (sg.z - THING_LO)], 1);
        if (i3 > 0) atomicAdd(&hist[(i3 - 1) * NTC + (sg.w - THING_LO)], 1);

        instw[q] = (uint32_t)i0 | ((uint32_t)i1 << 8) |
                   ((uint32_t)i2 << 16) | ((uint32_t)i3 << 24);
    }
    __syncthreads();

    for (int i = tid; i < NI * NTC; i += 256) {
        const int v = hist[i];
        if (v) atomicAdd(&counts[i], v);
    }
}

// K2: one block of 128 threads. argmax over the 10 thing-class counts
// (strict > from low class == jnp.argmax first-max; all-zero row -> class 0).
__global__ __launch_bounds__(128) void k2_stats(
    const int* __restrict__ counts, const float* __restrict__ iprobs,
    float* __restrict__ out, int* __restrict__ cls_ws, float* __restrict__ inv_ws)
{
    const int i = threadIdx.x;      // 0..127 -> instance id i+1
    int bestv = 0, bestc = 0, tot = 0;
    #pragma unroll
    for (int j = 0; j < NTC; ++j) {
        const int c = counts[i * NTC + j];
        tot += c;
        if (c > bestv) { bestv = c; bestc = THING_LO + j; }
    }
    cls_ws[i] = bestc;
    inv_ws[i] = 1.0f / (float)(tot > 0 ? tot : 1);
    out[OFF_CLASS + i] = (float)bestc;
    out[OFF_PROBS + i] = iprobs[i];
    out[OFF_SEGP  + i] = 0.0f;
    out[OFF_TOTAL + i] = (float)tot;
    out[OFF_VALID + i] = (tot > 0) ? 1.0f : 0.0f;
}

// K3 fused: one grid, two roles, so the read-bound seg-prob sweep overlaps
// the write-bound mask stream (complementary HBM directions).
//
// Seg role (blocks [0, 640)): STREAMED per-class sweep replacing the random
//   gather — block (c, chunk) streams 32 KB of inst words + 128 KB of plane
//   c of probs, predicate-accumulates probs into LDS bins where
//   scls[inst]==c. ~104 MB coalesced reads total vs ~617K cold scattered
//   loads before. Early-out for classes no instance argmax-maps to.
//
// Mask role (blocks [640, 2688)): unchanged full-occupancy streamer —
//   512 KB fully contiguous per block, 1 KB per wave store, reading inst
//   words from the L2-resident 2 MB workspace.
__global__ __launch_bounds__(256) void k3_fused(
    const uint32_t* __restrict__ instw, const float* __restrict__ probs,
    const int* __restrict__ cls_ws, const float* __restrict__ inv_ws,
    float* __restrict__ out)
{
    const int bid = blockIdx.x;
    const int tid = threadIdx.x;

    if (bid < SEG_BLOCKS) {
        // ---------------- seg-prob sweep role ----------------
        __shared__ int   scls[NI];
        __shared__ float lsum[NI];
        __shared__ int   anyflag;
        if (tid == 0) anyflag = 0;
        if (tid < NI) {
            scls[tid] = cls_ws[tid];
            lsum[tid] = 0.0f;
        }
        __syncthreads();
        const int c     = THING_LO + (bid >> 6);   // class 24..33
        const int chunk = bid & (NSEGCH - 1);      // 0..63
        if (tid < NI && scls[tid] == c) anyflag = 1;
        __syncthreads();
        if (!anyflag) return;                      // class unused by argmax

        const uint32_t* src = instw + (size_t)chunk * CW3;
        const float*    pp  = probs + (size_t)c * HWP + (size_t)chunk * (CW3 * 4);

        #pragma unroll 4
        for (int i = 0; i < CW3 / 256; ++i) {      // 32 iterations
            const int q = i * 256 + tid;
            const uint32_t wv = src[q];
            const nfloat4  pv = *reinterpret_cast<const nfloat4*>(pp + (size_t)q * 4);
            if (wv) {
                const int i0 =  wv        & 0xffu;
                const int i1 = (wv >> 8)  & 0xffu;
                const int i2 = (wv >> 16) & 0xffu;
                const int i3 =  wv >> 24;
                if (i0 && scls[i0 - 1] == c) atomicAdd(&lsum[i0 - 1], pv.x);
                if (i1 && scls[i1 - 1] == c) atomicAdd(&lsum[i1 - 1], pv.y);
                if (i2 && scls[i2 - 1] == c) atomicAdd(&lsum[i2 - 1], pv.z);
                if (i3 && scls[i3 - 1] == c) atomicAdd(&lsum[i3 - 1], pv.w);
            }
        }
        __syncthreads();
        if (tid < NI) {
            const float v = lsum[tid];
            if (v != 0.0f)
                atomicAdd(&out[OFF_SEGP + tid], v * inv_ws[tid]);
        }
    } else {
        // ---------------- mask streamer role ----------------
        const int bid2  = bid - SEG_BLOCKS;
        const int plane = bid2 & (NI - 1);         // 0..127
        const int chunk = bid2 >> 7;               // 0..15
        const uint32_t id = (uint32_t)(plane + 1); // instance id 1..128

        const uint32_t* src = instw + (size_t)chunk * CWORDS;
        float* dst = out + (size_t)plane * HWP + (size_t)chunk * CPIX;

        #pragma unroll 4
        for (int i = 0; i < CWORDS / 256; ++i) {   // 128 iterations
            const uint32_t qq = src[i * 256 + tid];
            nfloat4 v;
            v.x = ((qq & 0xffu)         == id) ? 1.0f : 0.0f;
            v.y = (((qq >> 8)  & 0xffu) == id) ? 1.0f : 0.0f;
            v.z = (((qq >> 16) & 0xffu) == id) ? 1.0f : 0.0f;
            v.w = ((qq >> 24)           == id) ? 1.0f : 0.0f;
            *reinterpret_cast<nfloat4*>(dst + (size_t)(i * 256 + tid) * 4) = v;
        }
    }
}

extern "C" void kernel_launch(void* const* d_in, const int* in_sizes, int n_in,
                              void* d_out, int out_size, void* d_ws, size_t ws_size,
                              hipStream_t stream) {
    const int*   seg    = (const int*)d_in[0];     // (H,W) int32
    const int*   imap   = (const int*)d_in[1];     // (H,W) int32
    const float* probs  = (const float*)d_in[2];   // (C,H,W) f32
    const float* iprobs = (const float*)d_in[3];   // (NI,) f32
    float* out = (float*)d_out;

    char* ws = (char*)d_ws;
    int*      counts = (int*)(ws + WS_COUNTS);
    int*      cls_ws = (int*)(ws + WS_CLS);
    float*    inv_ws = (float*)(ws + WS_INV);
    uint32_t* instw  = (uint32_t*)(ws + WS_INST);

    (void)hipMemsetAsync(counts, 0, NI * NTC * sizeof(int), stream);

    k1a_inst<<<K1A_BLOCKS, 256, 0, stream>>>(seg, imap, instw, counts);
    k2_stats<<<1, 128, 0, stream>>>(counts, iprobs, out, cls_ws, inv_ws);
    k3_fused<<<FUSED_BLOCKS, 256, 0, stream>>>(instw, probs, cls_ws, inv_ws, out);
}